// Round 7
// baseline (391.332 us; speedup 1.0000x reference)
//
#include <hip/hip_runtime.h>
#include <math.h>

#define HW 1024
#define PLANE (1024 * 1024)

// 9 possible grids (n in {20,30,40,65,80,95,125,150,175}), all compile-time:
//   g:      0    1    2    3    4    5    6    7    8
//   n:     20   30   40   65   80   95  125  150  175
//   gr:     4    5    6    8    9   10   11   12   13
//   gc:     5    6    7    9    9   10   12   13   14
// Unique column structures (gc): {5,6,7,9,10,12,13,14} -> 8 structures,
// 76 total col-cells, 84 boundary entries (incl. 0 and 1024).
__constant__ int GCS[8]   = {5, 6, 7, 9, 10, 12, 13, 14};
__constant__ int BBASE[8] = {0, 6, 13, 21, 31, 42, 55, 69};
__constant__ int GR9c[9]      = {4, 5, 6, 8, 9, 10, 11, 12, 13};
__constant__ int GC9c[9]      = {5, 6, 7, 9, 9, 10, 12, 13, 14};
__constant__ int GBASE9c[9]   = {0, 20, 50, 92, 164, 245, 345, 477, 633};  // cumsum gr*gc (815 total)
__constant__ int COLBASE9c[9] = {0, 5, 11, 18, 18, 27, 37, 49, 62};

// ws layout (float units):
// [0..2048)        per-block GLCM partials (256 blocks/batch * 8 batches)
// [2048..2056)     tier per batch (int)
// [2056..2064)     done-counter per batch (int, memset to 0 each call)
// [2080..8600)     cellmean, all 9 grids: 8 batches * 815 cells
// [16384..671744)  per-row column-cell records: 8 * 1024 rows * 80 (76 used)

__device__ __forceinline__ int wave_reduce_int(int v) {
#pragma unroll
    for (int off = 32; off > 0; off >>= 1) v += __shfl_down(v, off, 64);
    return v;
}
__device__ __forceinline__ float wave_reduce_f(float v) {
#pragma unroll
    for (int off = 32; off > 0; off >>= 1) v += __shfl_down(v, off, 64);
    return v;
}

// Kernel 1: grid (256, 8); 4 waves/block, one ROW per wave. Lane l owns float4
// chunks #l, #l+64, #l+128, #l+192 (every global load/store is a contiguous
// 1KB wave access). Per row: GLCM sq-diff partial; channel-mean -> wave scan
// -> boundary prefixes -> 76 column-cell sums -> rowrec.
// TAIL (threadfence-reduction): the last-finishing block of each batch
// reduces that batch's 256 GLCM partials -> complexity/tier/cluster_sets and
// folds all 815 cell means (9 grids) from rowrec -- removing the separate
// k_reduce dispatch and overlapping this work with other batches' blocks.
__global__ __launch_bounds__(256) void k_main(const float* __restrict__ img,
                                              float* __restrict__ partials,
                                              float* __restrict__ rowrec,
                                              float* __restrict__ cellmean,
                                              float* __restrict__ out,
                                              int* __restrict__ tier_ws,
                                              int* __restrict__ done_ctr) {
    const int b = blockIdx.y;
    const int tid = threadIdx.x;
    const int lane = tid & 63;
    const int w = tid >> 6;
    const int row = (blockIdx.x << 2) + w;

    const float* p = img + (size_t)b * (3 * PLANE) + row * HW;

    __shared__ float cmS[4][1024];
    __shared__ float PS[4][260];
    __shared__ float BS[4][88];
    __shared__ int swred[4];
    __shared__ int isLastS;
    __shared__ float credS[4];

    int acc = 0;
    int pend = 0;
    float csum[4];

#pragma unroll
    for (int j = 0; j < 4; ++j) {
        const int c = ((j << 6) + lane) << 2;
        const float4 R = *(const float4*)(p + c);
        const float4 G = *(const float4*)(p + PLANE + c);
        const float4 Bv = *(const float4*)(p + 2 * PLANE + c);

        const float m0 = (R.x + G.x + Bv.x) * (1.0f / 3.0f);
        const float m1 = (R.y + G.y + Bv.y) * (1.0f / 3.0f);
        const float m2 = (R.z + G.z + Bv.z) * (1.0f / 3.0f);
        const float m3 = (R.w + G.w + Bv.w) * (1.0f / 3.0f);
        *(float4*)&cmS[w][c] = make_float4(m0, m1, m2, m3);
        csum[j] = (m0 + m1) + (m2 + m3);

        const float g0 = 0.299f * R.x + 0.587f * G.x + 0.114f * Bv.x;
        const float g1 = 0.299f * R.y + 0.587f * G.y + 0.114f * Bv.y;
        const float g2 = 0.299f * R.z + 0.587f * G.z + 0.114f * Bv.z;
        const float g3 = 0.299f * R.w + 0.587f * G.w + 0.114f * Bv.w;

        const int gi0 = min(max((int)(g0 * 255.0f), 0), 255);
        const int gi1 = min(max((int)(g1 * 255.0f), 0), 255);
        const int gi2 = min(max((int)(g2 * 255.0f), 0), 255);
        const int gi3 = min(max((int)(g3 * 255.0f), 0), 255);

        const int first0 = __shfl(gi0, 0, 64);      // lane 0's first element
        if (j > 0 && lane == 63) {
            const int d = pend - first0;            // seam: chunk 63 -> chunk 64
            acc += d * d;
        }
        const int nxt = __shfl_down(gi0, 1, 64);    // next lane's first element
        const int d0 = gi0 - gi1, d1 = gi1 - gi2, d2 = gi2 - gi3;
        acc += d0 * d0 + d1 * d1 + d2 * d2;
        if (lane != 63) {
            const int d = gi3 - nxt;
            acc += d * d;
        }
        pend = gi3;
    }

    // Exclusive prefix of chunk sums over the whole row (wave scan).
    float pre = 0.0f;
#pragma unroll
    for (int j = 0; j < 4; ++j) {
        float x = csum[j];
#pragma unroll
        for (int off = 1; off < 64; off <<= 1) {
            const float y = __shfl_up(x, off, 64);
            if (lane >= off) x += y;
        }
        PS[w][(j << 6) + lane] = pre + (x - csum[j]);  // exclusive prefix of chunk
        pre += __shfl(x, 63, 64);
    }
    if (lane == 0) PS[w][256] = pre;  // row total (boundary col 1024)

    // Boundary prefixes B(c) for all 84 boundary entries (wave-local LDS).
#pragma unroll
    for (int rep = 0; rep < 2; ++rep) {
        const int bnd = lane + (rep << 6);
        if (bnd < 84) {
            const int sct = (bnd >= 6) + (bnd >= 13) + (bnd >= 21) + (bnd >= 31) +
                            (bnd >= 42) + (bnd >= 55) + (bnd >= 69);
            const int gc = GCS[sct];
            const int i = bnd - BBASE[sct];
            const int c = (i * 1024 + gc - 1) / gc;  // ceil(i*1024/gc)
            const int m = c & 3;
            const int cb = min(c & ~3, 1020);        // clamp for c==1024 (m==0)
            float Bp = PS[w][c >> 2];
            const float a0 = cmS[w][cb], a1 = cmS[w][cb + 1], a2 = cmS[w][cb + 2];
            if (m > 0) Bp += a0;
            if (m > 1) Bp += a1;
            if (m > 2) Bp += a2;
            BS[w][bnd] = Bp;
        }
    }

    // Column-cell sums = adjacent boundary differences -> per-row record.
    float* rr = rowrec + (size_t)((b << 10) + row) * 80;
#pragma unroll
    for (int rep = 0; rep < 2; ++rep) {
        const int k = lane + (rep << 6);
        if (k < 76) {
            const int sct = (k >= 5) + (k >= 11) + (k >= 18) + (k >= 27) +
                            (k >= 37) + (k >= 49) + (k >= 62);
            const int bidx = k + sct;
            rr[k] = BS[w][bidx + 1] - BS[w][bidx];
        }
    }

    acc = wave_reduce_int(acc);  // exact int within block
    if (lane == 0) swred[w] = acc;
    __syncthreads();
    if (tid == 0)
        partials[(b << 8) + blockIdx.x] = (float)(swred[0] + swred[1] + swred[2] + swred[3]);

    // ---- Last-block-per-batch fold (threadfence reduction pattern) ----
    __threadfence();  // release: rowrec + partials visible device-wide
    if (tid == 0) {
        const int old = atomicAdd(&done_ctr[b], 1);  // device-scope
        isLastS = (old == 255);
    }
    __syncthreads();
    if (!isLastS) return;
    __threadfence();  // acquire: see all batch-b blocks' rowrec/partials

    // (a) complexity -> tier -> complexity & cluster_sets outputs
    {
        float v = partials[(b << 8) + tid];
        v = wave_reduce_f(v);
        if (lane == 0) credS[w] = v;
        __syncthreads();
        if (tid == 0) {
            const size_t OFFC = (size_t)8 * 3 * PLANE;
            const float cv = (credS[0] + credS[1] + credS[2] + credS[3]) *
                             (1.0f / (1024.0f * 1023.0f));
            out[OFFC + b] = cv;
            const int tier = (cv < 50.0f) ? 0 : ((cv < 150.0f) ? 1 : 2);
            const int kk = (tier == 0) ? 30 : ((tier == 1) ? 80 : 150);
            const int dd = (tier == 0) ? 10 : ((tier == 1) ? 15 : 25);
#pragma unroll
            for (int j = 0; j < 3; ++j)
                out[OFFC + 8 + b * 3 + j] = (float)(kk + (j - 1) * dd);  // int vals, f32 buf
            tier_ws[b] = tier;
        }
    }

    // (b) all 815 cell means for this batch (9 grids), 256 threads stride.
    for (int ci = tid; ci < 815; ci += 256) {
        const int g = (ci >= 20) + (ci >= 50) + (ci >= 92) + (ci >= 164) +
                      (ci >= 245) + (ci >= 345) + (ci >= 477) + (ci >= 633);
        const int gr = GR9c[g], gc = GC9c[g];
        const int local = ci - GBASE9c[g];
        const int rc = local / gc, cc = local - rc * gc;
        const int cb = COLBASE9c[g];
        const int r0 = (rc * 1024 + gr - 1) / gr;
        const int r1 = ((rc + 1) * 1024 + gr - 1) / gr;
        const int c0 = (cc * 1024 + gc - 1) / gc;
        const int c1 = ((cc + 1) * 1024 + gc - 1) / gc;
        float s = 0.0f;
        const float* rbase = rowrec + (size_t)(b << 10) * 80 + cb + cc;
        for (int r = r0; r < r1; ++r) s += rbase[(size_t)r * 80];
        const float area = (float)((r1 - r0) * (c1 - c0));
        cellmean[b * 815 + ci] = s / area;
    }
}

// Kernel 2: fill saliency; 4 rows per block (grid 256 x 3 x 8), one float4
// store per thread per row. Grid index is tier*3 + map.
__global__ __launch_bounds__(256) void k_fill(const int* __restrict__ tier_ws,
                                              const float* __restrict__ cellmean,
                                              float* __restrict__ out) {
    const int jm = blockIdx.y, b = blockIdx.z;
    const int tid = threadIdx.x;
    const int g = tier_ws[b] * 3 + jm;
    const int gr = GR9c[g], gc = GC9c[g];
    const float* cmb = cellmean + b * 815 + GBASE9c[g];
    float* ob = out + ((size_t)(b * 3 + jm) << 20);
    const int col = tid << 2;
    const int i0 = (col * gc) >> 10, i1 = ((col + 1) * gc) >> 10;
    const int i2 = ((col + 2) * gc) >> 10, i3 = ((col + 3) * gc) >> 10;

#pragma unroll
    for (int i = 0; i < 4; ++i) {
        const int row = (blockIdx.x << 2) + i;
        const int rc = (row * gr) >> 10;
        const float* cm = cmb + rc * gc;
        float4 o;
        o.x = cm[i0];
        o.y = cm[i1];
        o.z = cm[i2];
        o.w = cm[i3];
        *(float4*)(ob + row * HW + col) = o;
    }
}

extern "C" void kernel_launch(void* const* d_in, const int* in_sizes, int n_in,
                              void* d_out, int out_size, void* d_ws, size_t ws_size,
                              hipStream_t stream) {
    const float* img = (const float*)d_in[0];
    float* out = (float*)d_out;
    float* ws = (float*)d_ws;

    float* partials = ws;               // 2048 floats
    int* tier_ws = (int*)(ws + 2048);   // 8 ints
    int* done_ctr = (int*)(ws + 2056);  // 8 ints, zeroed each call
    float* cellmean = ws + 2080;        // 8*815 floats
    float* rowrec = ws + 16384;         // 8*1024*80 floats (2.6 MB)

    hipMemsetAsync((void*)done_ctr, 0, 8 * sizeof(int), stream);
    k_main<<<dim3(256, 8), 256, 0, stream>>>(img, partials, rowrec, cellmean, out,
                                             tier_ws, done_ctr);
    k_fill<<<dim3(256, 3, 8), 256, 0, stream>>>(tier_ws, cellmean, out);
}

// Round 8
// 46.254 us; speedup vs baseline: 8.4604x; 8.4604x over previous
//
#include <hip/hip_runtime.h>
#include <math.h>

#define HW 1024
#define PLANE (1024 * 1024)

typedef float vf4 __attribute__((ext_vector_type(4)));

// 9 possible grids (n in {20,30,40,65,80,95,125,150,175}), all compile-time:
//   g:      0    1    2    3    4    5    6    7    8
//   n:     20   30   40   65   80   95  125  150  175
//   gr:     4    5    6    8    9   10   11   12   13
//   gc:     5    6    7    9    9   10   12   13   14
// Unique column structures (gc): {5,6,7,9,10,12,13,14} -> 8 structures,
// 76 total col-cells, 84 boundary entries (incl. 0 and 1024).
__constant__ int GCS[8]   = {5, 6, 7, 9, 10, 12, 13, 14};
__constant__ int BBASE[8] = {0, 6, 13, 21, 31, 42, 55, 69};
__constant__ int GR9c[9]      = {4, 5, 6, 8, 9, 10, 11, 12, 13};
__constant__ int GC9c[9]      = {5, 6, 7, 9, 9, 10, 12, 13, 14};
__constant__ int GBASE9c[9]   = {0, 20, 50, 92, 164, 245, 345, 477, 633};  // cumsum gr*gc (815 total)
__constant__ int COLBASE9c[9] = {0, 5, 11, 18, 18, 27, 37, 49, 62};

// ws layout (float units):
// [0..2048)        per-block GLCM partials (256 blocks/batch * 8 batches)
// [2048..2056)     tier per batch (int)
// [2080..8600)     cellmean, all 9 grids: 8 batches * 815 cells
// [16384..671744)  per-row column-cell records: 8 * 1024 rows * 80 (76 used)
//
// NOTE (r5/r7 lessons): no grid-wide sync, no device-scope fences/atomic
// folds -- both cost 10x the dispatch they save on 8 non-coherent XCD L2s.

__device__ __forceinline__ int wave_reduce_int(int v) {
#pragma unroll
    for (int off = 32; off > 0; off >>= 1) v += __shfl_down(v, off, 64);
    return v;
}

// Kernel 1: grid (256, 8); 4 waves/block, one ROW per wave. Lane l owns float4
// chunks #l, #l+64, #l+128, #l+192 (every global load is a contiguous 1KB wave
// access). img is read ONCE -> nontemporal loads (don't displace rowrec in
// L2). Per row: GLCM sq-diff partial; channel-mean -> wave scan -> boundary
// prefixes -> 76 column-cell sums -> rowrec (cached: re-read by k_reduce).
__global__ __launch_bounds__(256) void k_main(const float* __restrict__ img,
                                              float* __restrict__ partials,
                                              float* __restrict__ rowrec) {
    const int b = blockIdx.y;
    const int tid = threadIdx.x;
    const int lane = tid & 63;
    const int w = tid >> 6;
    const int row = (blockIdx.x << 2) + w;

    const float* p = img + (size_t)b * (3 * PLANE) + row * HW;

    __shared__ float cmS[4][1024];
    __shared__ float PS[4][260];
    __shared__ float BS[4][88];
    __shared__ int swred[4];

    // Hoisted nontemporal loads: all 12 in flight before any dependent use.
    vf4 R[4], G[4], Bv[4];
#pragma unroll
    for (int j = 0; j < 4; ++j) {
        const int c = ((j << 6) + lane) << 2;
        R[j] = __builtin_nontemporal_load((const vf4*)(p + c));
        G[j] = __builtin_nontemporal_load((const vf4*)(p + PLANE + c));
        Bv[j] = __builtin_nontemporal_load((const vf4*)(p + 2 * PLANE + c));
    }

    int acc = 0;
    int pend = 0;
    float csum[4];

#pragma unroll
    for (int j = 0; j < 4; ++j) {
        const int c = ((j << 6) + lane) << 2;

        const float m0 = (R[j].x + G[j].x + Bv[j].x) * (1.0f / 3.0f);
        const float m1 = (R[j].y + G[j].y + Bv[j].y) * (1.0f / 3.0f);
        const float m2 = (R[j].z + G[j].z + Bv[j].z) * (1.0f / 3.0f);
        const float m3 = (R[j].w + G[j].w + Bv[j].w) * (1.0f / 3.0f);
        *(float4*)&cmS[w][c] = make_float4(m0, m1, m2, m3);
        csum[j] = (m0 + m1) + (m2 + m3);

        const float g0 = 0.299f * R[j].x + 0.587f * G[j].x + 0.114f * Bv[j].x;
        const float g1 = 0.299f * R[j].y + 0.587f * G[j].y + 0.114f * Bv[j].y;
        const float g2 = 0.299f * R[j].z + 0.587f * G[j].z + 0.114f * Bv[j].z;
        const float g3 = 0.299f * R[j].w + 0.587f * G[j].w + 0.114f * Bv[j].w;

        const int gi0 = min(max((int)(g0 * 255.0f), 0), 255);
        const int gi1 = min(max((int)(g1 * 255.0f), 0), 255);
        const int gi2 = min(max((int)(g2 * 255.0f), 0), 255);
        const int gi3 = min(max((int)(g3 * 255.0f), 0), 255);

        const int first0 = __shfl(gi0, 0, 64);      // lane 0's first element
        if (j > 0 && lane == 63) {
            const int d = pend - first0;            // seam: chunk 63 -> chunk 64
            acc += d * d;
        }
        const int nxt = __shfl_down(gi0, 1, 64);    // next lane's first element
        const int d0 = gi0 - gi1, d1 = gi1 - gi2, d2 = gi2 - gi3;
        acc += d0 * d0 + d1 * d1 + d2 * d2;
        if (lane != 63) {
            const int d = gi3 - nxt;
            acc += d * d;
        }
        pend = gi3;
    }

    // Exclusive prefix of chunk sums over the whole row (wave scan).
    float pre = 0.0f;
#pragma unroll
    for (int j = 0; j < 4; ++j) {
        float x = csum[j];
#pragma unroll
        for (int off = 1; off < 64; off <<= 1) {
            const float y = __shfl_up(x, off, 64);
            if (lane >= off) x += y;
        }
        PS[w][(j << 6) + lane] = pre + (x - csum[j]);  // exclusive prefix of chunk
        pre += __shfl(x, 63, 64);
    }
    if (lane == 0) PS[w][256] = pre;  // row total (boundary col 1024)

    // Boundary prefixes B(c) for all 84 boundary entries (wave-local LDS).
#pragma unroll
    for (int rep = 0; rep < 2; ++rep) {
        const int bnd = lane + (rep << 6);
        if (bnd < 84) {
            const int sct = (bnd >= 6) + (bnd >= 13) + (bnd >= 21) + (bnd >= 31) +
                            (bnd >= 42) + (bnd >= 55) + (bnd >= 69);
            const int gc = GCS[sct];
            const int i = bnd - BBASE[sct];
            const int c = (i * 1024 + gc - 1) / gc;  // ceil(i*1024/gc)
            const int m = c & 3;
            const int cb = min(c & ~3, 1020);        // clamp for c==1024 (m==0)
            float Bp = PS[w][c >> 2];
            const float a0 = cmS[w][cb], a1 = cmS[w][cb + 1], a2 = cmS[w][cb + 2];
            if (m > 0) Bp += a0;
            if (m > 1) Bp += a1;
            if (m > 2) Bp += a2;
            BS[w][bnd] = Bp;
        }
    }

    // Column-cell sums = adjacent boundary differences -> per-row record.
    float* rr = rowrec + (size_t)((b << 10) + row) * 80;
#pragma unroll
    for (int rep = 0; rep < 2; ++rep) {
        const int k = lane + (rep << 6);
        if (k < 76) {
            const int sct = (k >= 5) + (k >= 11) + (k >= 18) + (k >= 27) +
                            (k >= 37) + (k >= 49) + (k >= 62);
            const int bidx = k + sct;
            rr[k] = BS[w][bidx + 1] - BS[w][bidx];
        }
    }

    acc = wave_reduce_int(acc);  // exact int within block
    if (lane == 0) swred[w] = acc;
    __syncthreads();
    if (tid == 0)
        partials[(b << 8) + blockIdx.x] = (float)(swred[0] + swred[1] + swred[2] + swred[3]);
}

// Kernel 2: grid (13, 9, 8): block (rc, g, b) reduces rows of row-cell rc for
// grid g -> cell means (all 9 grids, independent of tier). Block (0,0,0) also
// finalizes complexity, writes complexity + cluster_sets outputs and tier[].
__global__ __launch_bounds__(256) void k_reduce(const float* __restrict__ rowrec,
                                                const float* __restrict__ partials,
                                                float* __restrict__ cellmean,
                                                float* __restrict__ out,
                                                int* __restrict__ tier_ws) {
    const int rc = blockIdx.x, g = blockIdx.y, b = blockIdx.z;
    const int t = threadIdx.x;
    const int gr = GR9c[g];
    const bool active = (rc < gr);

    __shared__ float red[16][17];
    __shared__ float compLDS[8];

    const int gc = GC9c[g];
    const int cb = COLBASE9c[g];
    const int r0 = (rc * 1024 + gr - 1) / gr;
    const int r1 = ((rc + 1) * 1024 + gr - 1) / gr;
    const int cc = t & 15, rch = t >> 4;

    if (active) {
        float s = 0.0f;
        if (cc < gc)
            for (int r = r0 + rch; r < r1; r += 16)
                s += rowrec[(size_t)((b << 10) + r) * 80 + cb + cc];
        red[rch][cc] = s;
    }

    const bool special = (rc == 0 && g == 0 && b == 0);
    if (special) {
        const int b2 = t >> 5, sub = t & 31;
        float sC = 0.0f;
#pragma unroll
        for (int kk = 0; kk < 8; ++kk) sC += partials[(b2 << 8) + sub + (kk << 5)];
#pragma unroll
        for (int off = 16; off > 0; off >>= 1) sC += __shfl_down(sC, off, 32);
        if (sub == 0) compLDS[b2] = sC;
    }

    __syncthreads();

    if (active && rch == 0 && cc < gc) {
        float tot = 0.0f;
#pragma unroll
        for (int q = 0; q < 16; ++q) tot += red[q][cc];
        const int c0 = (cc * 1024 + gc - 1) / gc;
        const int c1 = ((cc + 1) * 1024 + gc - 1) / gc;
        const float area = (float)((r1 - r0) * (c1 - c0));
        cellmean[b * 815 + GBASE9c[g] + rc * gc + cc] = tot / area;
    }

    if (special && t < 8) {
        const size_t OFFC = (size_t)8 * 3 * PLANE;
        const float cv = compLDS[t] * (1.0f / (1024.0f * 1023.0f));
        out[OFFC + t] = cv;
        const int tier = (cv < 50.0f) ? 0 : ((cv < 150.0f) ? 1 : 2);
        const int kk = (tier == 0) ? 30 : ((tier == 1) ? 80 : 150);
        const int dd = (tier == 0) ? 10 : ((tier == 1) ? 15 : 25);
#pragma unroll
        for (int j = 0; j < 3; ++j)
            out[OFFC + 8 + t * 3 + j] = (float)(kk + (j - 1) * dd);  // int32 values, f32 buffer
        tier_ws[t] = tier;
    }
}

// Kernel 3: fill saliency; 4 rows per block (grid 256 x 3 x 8). Output is
// written once and never re-read -> nontemporal stores.
__global__ __launch_bounds__(256) void k_fill(const int* __restrict__ tier_ws,
                                              const float* __restrict__ cellmean,
                                              float* __restrict__ out) {
    const int jm = blockIdx.y, b = blockIdx.z;
    const int tid = threadIdx.x;
    const int g = tier_ws[b] * 3 + jm;
    const int gr = GR9c[g], gc = GC9c[g];
    const float* cmb = cellmean + b * 815 + GBASE9c[g];
    float* ob = out + ((size_t)(b * 3 + jm) << 20);
    const int col = tid << 2;
    const int i0 = (col * gc) >> 10, i1 = ((col + 1) * gc) >> 10;
    const int i2 = ((col + 2) * gc) >> 10, i3 = ((col + 3) * gc) >> 10;

#pragma unroll
    for (int i = 0; i < 4; ++i) {
        const int row = (blockIdx.x << 2) + i;
        const int rc = (row * gr) >> 10;
        const float* cm = cmb + rc * gc;
        vf4 o;
        o.x = cm[i0];
        o.y = cm[i1];
        o.z = cm[i2];
        o.w = cm[i3];
        __builtin_nontemporal_store(o, (vf4*)(ob + row * HW + col));
    }
}

extern "C" void kernel_launch(void* const* d_in, const int* in_sizes, int n_in,
                              void* d_out, int out_size, void* d_ws, size_t ws_size,
                              hipStream_t stream) {
    const float* img = (const float*)d_in[0];
    float* out = (float*)d_out;
    float* ws = (float*)d_ws;

    float* partials = ws;              // 2048 floats
    int* tier_ws = (int*)(ws + 2048);  // 8 ints
    float* cellmean = ws + 2080;       // 8*815 floats
    float* rowrec = ws + 16384;        // 8*1024*80 floats (2.6 MB)

    k_main<<<dim3(256, 8), 256, 0, stream>>>(img, partials, rowrec);
    k_reduce<<<dim3(13, 9, 8), 256, 0, stream>>>(rowrec, partials, cellmean, out, tier_ws);
    k_fill<<<dim3(256, 3, 8), 256, 0, stream>>>(tier_ws, cellmean, out);
}

// Round 9
// 44.741 us; speedup vs baseline: 8.7467x; 1.0338x over previous
//
#include <hip/hip_runtime.h>
#include <math.h>

#define HW 1024
#define PLANE (1024 * 1024)

typedef float vf4 __attribute__((ext_vector_type(4)));

// 9 possible grids (n in {20,30,40,65,80,95,125,150,175}), all compile-time:
//   g:      0    1    2    3    4    5    6    7    8
//   n:     20   30   40   65   80   95  125  150  175
//   gr:     4    5    6    8    9   10   11   12   13
//   gc:     5    6    7    9    9   10   12   13   14
// Unique column structures (gc): {5,6,7,9,10,12,13,14} -> 8 structures,
// 76 total col-cells, 84 boundary entries (incl. 0 and 1024).
__constant__ int GCS[8]   = {5, 6, 7, 9, 10, 12, 13, 14};
__constant__ int BBASE[8] = {0, 6, 13, 21, 31, 42, 55, 69};
__constant__ int GR9c[9]      = {4, 5, 6, 8, 9, 10, 11, 12, 13};
__constant__ int GC9c[9]      = {5, 6, 7, 9, 9, 10, 12, 13, 14};
__constant__ int COLBASE9c[9] = {0, 5, 11, 18, 18, 27, 37, 49, 62};

// ws layout (float units):
// [0..2048)        per-block GLCM partials (256 blocks/batch * 8 batches)
// [16384..671744)  per-row column-cell records: 8 * 1024 rows * 80 (76 used)
//
// NOTE (r5/r7 lessons): no grid-wide sync, no device-scope fences/atomic
// folds -- both cost 10x the dispatch they save on 8 non-coherent XCD L2s.
// Redundant per-block recompute from L2/L3-resident data is the right way
// to drop a dispatch (this round).

__device__ __forceinline__ int wave_reduce_int(int v) {
#pragma unroll
    for (int off = 32; off > 0; off >>= 1) v += __shfl_down(v, off, 64);
    return v;
}
__device__ __forceinline__ float wave_reduce_f(float v) {
#pragma unroll
    for (int off = 32; off > 0; off >>= 1) v += __shfl_down(v, off, 64);
    return v;
}

// Kernel 1: grid (256, 8); 4 waves/block, one ROW per wave. Lane l owns float4
// chunks #l, #l+64, #l+128, #l+192 (every global load is a contiguous 1KB wave
// access). img is read ONCE -> nontemporal loads. Per row: GLCM sq-diff
// partial; channel-mean -> wave scan -> boundary prefixes -> 76 column-cell
// sums -> rowrec (cached: re-read by k_fill2).
__global__ __launch_bounds__(256) void k_main(const float* __restrict__ img,
                                              float* __restrict__ partials,
                                              float* __restrict__ rowrec) {
    const int b = blockIdx.y;
    const int tid = threadIdx.x;
    const int lane = tid & 63;
    const int w = tid >> 6;
    const int row = (blockIdx.x << 2) + w;

    const float* p = img + (size_t)b * (3 * PLANE) + row * HW;

    __shared__ float cmS[4][1024];
    __shared__ float PS[4][260];
    __shared__ float BS[4][88];
    __shared__ int swred[4];

    // Hoisted nontemporal loads: all 12 in flight before any dependent use.
    vf4 R[4], G[4], Bv[4];
#pragma unroll
    for (int j = 0; j < 4; ++j) {
        const int c = ((j << 6) + lane) << 2;
        R[j] = __builtin_nontemporal_load((const vf4*)(p + c));
        G[j] = __builtin_nontemporal_load((const vf4*)(p + PLANE + c));
        Bv[j] = __builtin_nontemporal_load((const vf4*)(p + 2 * PLANE + c));
    }

    int acc = 0;
    int pend = 0;
    float csum[4];

#pragma unroll
    for (int j = 0; j < 4; ++j) {
        const int c = ((j << 6) + lane) << 2;

        const float m0 = (R[j].x + G[j].x + Bv[j].x) * (1.0f / 3.0f);
        const float m1 = (R[j].y + G[j].y + Bv[j].y) * (1.0f / 3.0f);
        const float m2 = (R[j].z + G[j].z + Bv[j].z) * (1.0f / 3.0f);
        const float m3 = (R[j].w + G[j].w + Bv[j].w) * (1.0f / 3.0f);
        *(float4*)&cmS[w][c] = make_float4(m0, m1, m2, m3);
        csum[j] = (m0 + m1) + (m2 + m3);

        const float g0 = 0.299f * R[j].x + 0.587f * G[j].x + 0.114f * Bv[j].x;
        const float g1 = 0.299f * R[j].y + 0.587f * G[j].y + 0.114f * Bv[j].y;
        const float g2 = 0.299f * R[j].z + 0.587f * G[j].z + 0.114f * Bv[j].z;
        const float g3 = 0.299f * R[j].w + 0.587f * G[j].w + 0.114f * Bv[j].w;

        const int gi0 = min(max((int)(g0 * 255.0f), 0), 255);
        const int gi1 = min(max((int)(g1 * 255.0f), 0), 255);
        const int gi2 = min(max((int)(g2 * 255.0f), 0), 255);
        const int gi3 = min(max((int)(g3 * 255.0f), 0), 255);

        const int first0 = __shfl(gi0, 0, 64);      // lane 0's first element
        if (j > 0 && lane == 63) {
            const int d = pend - first0;            // seam: chunk 63 -> chunk 64
            acc += d * d;
        }
        const int nxt = __shfl_down(gi0, 1, 64);    // next lane's first element
        const int d0 = gi0 - gi1, d1 = gi1 - gi2, d2 = gi2 - gi3;
        acc += d0 * d0 + d1 * d1 + d2 * d2;
        if (lane != 63) {
            const int d = gi3 - nxt;
            acc += d * d;
        }
        pend = gi3;
    }

    // Exclusive prefix of chunk sums over the whole row (wave scan).
    float pre = 0.0f;
#pragma unroll
    for (int j = 0; j < 4; ++j) {
        float x = csum[j];
#pragma unroll
        for (int off = 1; off < 64; off <<= 1) {
            const float y = __shfl_up(x, off, 64);
            if (lane >= off) x += y;
        }
        PS[w][(j << 6) + lane] = pre + (x - csum[j]);  // exclusive prefix of chunk
        pre += __shfl(x, 63, 64);
    }
    if (lane == 0) PS[w][256] = pre;  // row total (boundary col 1024)

    // Boundary prefixes B(c) for all 84 boundary entries (wave-local LDS).
#pragma unroll
    for (int rep = 0; rep < 2; ++rep) {
        const int bnd = lane + (rep << 6);
        if (bnd < 84) {
            const int sct = (bnd >= 6) + (bnd >= 13) + (bnd >= 21) + (bnd >= 31) +
                            (bnd >= 42) + (bnd >= 55) + (bnd >= 69);
            const int gc = GCS[sct];
            const int i = bnd - BBASE[sct];
            const int c = (i * 1024 + gc - 1) / gc;  // ceil(i*1024/gc)
            const int m = c & 3;
            const int cb = min(c & ~3, 1020);        // clamp for c==1024 (m==0)
            float Bp = PS[w][c >> 2];
            const float a0 = cmS[w][cb], a1 = cmS[w][cb + 1], a2 = cmS[w][cb + 2];
            if (m > 0) Bp += a0;
            if (m > 1) Bp += a1;
            if (m > 2) Bp += a2;
            BS[w][bnd] = Bp;
        }
    }

    // Column-cell sums = adjacent boundary differences -> per-row record.
    float* rr = rowrec + (size_t)((b << 10) + row) * 80;
#pragma unroll
    for (int rep = 0; rep < 2; ++rep) {
        const int k = lane + (rep << 6);
        if (k < 76) {
            const int sct = (k >= 5) + (k >= 11) + (k >= 18) + (k >= 27) +
                            (k >= 37) + (k >= 49) + (k >= 62);
            const int bidx = k + sct;
            rr[k] = BS[w][bidx + 1] - BS[w][bidx];
        }
    }

    acc = wave_reduce_int(acc);  // exact int within block
    if (lane == 0) swred[w] = acc;
    __syncthreads();
    if (tid == 0)
        partials[(b << 8) + blockIdx.x] = (float)(swred[0] + swred[1] + swred[2] + swred[3]);
}

// Kernel 2 (self-sufficient fill): grid (256, 3, 8); block = 4 rows of one
// (batch, map). Each block independently: (a) reduces the batch's 256 GLCM
// partials -> complexity/tier (deterministic order -> identical in every
// block; 1KB L2-resident), (b) computes the 1-2 row-cells x gc cell means its
// rows need from rowrec (L2/L3-resident), (c) writes 4 output rows (NT).
// Block (0,0,b) also writes complexity + cluster_sets. Redundant recompute
// replaces the k_reduce dispatch (r5/r7 lesson: never sync, recompute).
__global__ __launch_bounds__(256) void k_fill2(const float* __restrict__ partials,
                                               const float* __restrict__ rowrec,
                                               float* __restrict__ out) {
    const int rblk = blockIdx.x, jm = blockIdx.y, b = blockIdx.z;
    const int tid = threadIdx.x;
    const int lane = tid & 63, w = tid >> 6;

    __shared__ float compLDS[4];
    __shared__ int tierS;
    __shared__ float red[16][17];
    __shared__ float cmLDS[2][16];

    // (a) tier from GLCM partials.
    float v = partials[(b << 8) + tid];
    v = wave_reduce_f(v);
    if (lane == 0) compLDS[w] = v;
    __syncthreads();
    if (tid == 0) {
        const float cv = (compLDS[0] + compLDS[1] + compLDS[2] + compLDS[3]) *
                         (1.0f / (1024.0f * 1023.0f));
        const int tier = (cv < 50.0f) ? 0 : ((cv < 150.0f) ? 1 : 2);
        tierS = tier;
        if (rblk == 0 && jm == 0) {
            const size_t OFFC = (size_t)8 * 3 * PLANE;
            out[OFFC + b] = cv;
            const int kk = (tier == 0) ? 30 : ((tier == 1) ? 80 : 150);
            const int dd = (tier == 0) ? 10 : ((tier == 1) ? 15 : 25);
#pragma unroll
            for (int j = 0; j < 3; ++j)
                out[OFFC + 8 + b * 3 + j] = (float)(kk + (j - 1) * dd);  // int vals, f32 buf
        }
    }
    __syncthreads();

    const int g = tierS * 3 + jm;
    const int gr = GR9c[g], gc = GC9c[g], cb = COLBASE9c[g];
    const int row0 = rblk << 2;
    const int rc0 = (row0 * gr) >> 10;
    const int rc3 = ((row0 + 3) * gr) >> 10;  // <= rc0+1 (cells are >=78 rows)

    // (b) cell means for the touched row-cells.
    const int cc = tid & 15, rch = tid >> 4;
    for (int rc = rc0; rc <= rc3; ++rc) {
        const int r0 = (rc * 1024 + gr - 1) / gr;
        const int r1 = ((rc + 1) * 1024 + gr - 1) / gr;
        float s = 0.0f;
        if (cc < gc)
            for (int r = r0 + rch; r < r1; r += 16)
                s += rowrec[(size_t)((b << 10) + r) * 80 + cb + cc];
        red[rch][cc] = s;
        __syncthreads();
        if (rch == 0 && cc < gc) {
            float tot = 0.0f;
#pragma unroll
            for (int q = 0; q < 16; ++q) tot += red[q][cc];
            const int c0 = (cc * 1024 + gc - 1) / gc;
            const int c1 = ((cc + 1) * 1024 + gc - 1) / gc;
            const float area = (float)((r1 - r0) * (c1 - c0));
            cmLDS[rc - rc0][cc] = tot / area;
        }
        __syncthreads();
    }

    // (c) write 4 rows (never re-read -> nontemporal).
    const int col = tid << 2;
    const int i0 = (col * gc) >> 10, i1 = ((col + 1) * gc) >> 10;
    const int i2 = ((col + 2) * gc) >> 10, i3 = ((col + 3) * gc) >> 10;
    float* ob = out + ((size_t)(b * 3 + jm) << 20);
#pragma unroll
    for (int i = 0; i < 4; ++i) {
        const int row = row0 + i;
        const int rc = (row * gr) >> 10;
        const float* cm = cmLDS[rc - rc0];
        vf4 o;
        o.x = cm[i0];
        o.y = cm[i1];
        o.z = cm[i2];
        o.w = cm[i3];
        __builtin_nontemporal_store(o, (vf4*)(ob + row * HW + col));
    }
}

extern "C" void kernel_launch(void* const* d_in, const int* in_sizes, int n_in,
                              void* d_out, int out_size, void* d_ws, size_t ws_size,
                              hipStream_t stream) {
    const float* img = (const float*)d_in[0];
    float* out = (float*)d_out;
    float* ws = (float*)d_ws;

    float* partials = ws;       // 2048 floats
    float* rowrec = ws + 16384; // 8*1024*80 floats (2.6 MB)

    k_main<<<dim3(256, 8), 256, 0, stream>>>(img, partials, rowrec);
    k_fill2<<<dim3(256, 3, 8), 256, 0, stream>>>(partials, rowrec, out);
}